// Round 7
// baseline (85.014 us; speedup 1.0000x reference)
//
#include <hip/hip_runtime.h>
#include <hip/hip_bf16.h>

#define NB    16
#define NQ    2048
#define NKV   2048
#define DH    128
#define KVT   64
#define NTILE 32          // NKV / KVT
#define TILE_BYTES 16384  // 64*128*2
#define TILE_ELT   8192

typedef __attribute__((ext_vector_type(8))) short short8;
typedef __attribute__((ext_vector_type(4))) float f32x4;

__device__ __forceinline__ unsigned short f2bf(float f) {
    union { float f; unsigned int u; } x; x.f = f;
    unsigned int r = (x.u + 0x7fffu + ((x.u >> 16) & 1u)) >> 16;
    return (unsigned short)r;
}

__device__ __forceinline__ void load_lds16(const void* g, void* l) {
    __builtin_amdgcn_global_load_lds(
        (const __attribute__((address_space(1))) unsigned int*)g,
        (__attribute__((address_space(3))) unsigned int*)l, 16, 0, 0);
}

// ---------------- pre-convert K -> bf16 tiles, V -> V^T bf16 tiles -----------
__global__ __launch_bounds__(256)
void preconv(const float* __restrict__ kg, const float* __restrict__ vg,
             const int* __restrict__ vlg,
             unsigned short* __restrict__ kws, unsigned short* __restrict__ vws) {
    __shared__ __align__(16) unsigned short lv[TILE_ELT];   // 16 KB temp
    const int tid = threadIdx.x;
    const int rb = (blockIdx.x & 7) * 64 + (blockIdx.x >> 3);   // XCD chunking
    const int b = rb >> 5, t = rb & 31;
    const int vl = vlg[b];
    const int ntiles = (vl == 0) ? NTILE : ((vl + KVT - 1) >> 6);
    if (t >= ntiles) return;

    const float* kb = kg + ((size_t)b * NKV + t * KVT) * DH;
    const float* vb = vg + ((size_t)b * NKV + t * KVT) * DH;
    char* kimg = (char*)(kws + (size_t)(b * NTILE + t) * TILE_ELT);
    char* vimg = (char*)(vws + (size_t)(b * NTILE + t) * TILE_ELT);

    #pragma unroll
    for (int p = 0; p < 4; ++p) {
        int idx = p * 256 + tid;
        int row = idx >> 4, ch = idx & 15;
        f32x4 a = *(const f32x4*)(kb + row * DH + ch * 8);
        f32x4 c = *(const f32x4*)(kb + row * DH + ch * 8 + 4);
        union { short8 v; unsigned short u[8]; } w;
        #pragma unroll
        for (int j = 0; j < 4; ++j) { w.u[j] = f2bf(a[j]); w.u[4 + j] = f2bf(c[j]); }
        *(short8*)(kimg + row * 256 + ((ch * 16) ^ ((row & 7) << 4))) = w.v;
        f32x4 va = *(const f32x4*)(vb + row * DH + ch * 8);
        f32x4 vc = *(const f32x4*)(vb + row * DH + ch * 8 + 4);
        union { short8 v; unsigned short u[8]; } w2;
        #pragma unroll
        for (int j = 0; j < 4; ++j) { w2.u[j] = f2bf(va[j]); w2.u[4 + j] = f2bf(vc[j]); }
        *(short8*)((char*)lv + row * 256 + ((ch * 16) ^ (((row >> 3) & 7) << 4))) = w2.v;
    }
    __syncthreads();
    #pragma unroll
    for (int p = 0; p < 4; ++p) {
        int task = p * 256 + tid;
        int c = task & 7, d = task >> 3;
        union { short8 v; unsigned short u[8]; } w;
        #pragma unroll
        for (int j = 0; j < 8; ++j) {
            int kv = c * 8 + j;
            w.u[j] = *(const unsigned short*)((const char*)lv + kv * 256 + ((d * 2) ^ (((kv >> 3) & 7) << 4)));
        }
        *(short8*)(vimg + d * 128 + ((c * 16) ^ ((d & 7) << 4))) = w.v;
    }
}

// --- split-KV attention: 4 waves x 32 q-rows (128 q/block), shared K/V reads -
__global__ __launch_bounds__(256, 3)
void attn_split(const float* __restrict__ qg,
                const unsigned short* __restrict__ kws,
                const unsigned short* __restrict__ vws,
                const int* __restrict__ vlg,
                float* __restrict__ og,       // used when S==1
                float* __restrict__ opart,    // [S][NB][NQ][DH] unnormalized
                float* __restrict__ ellg,     // [S][NB][NQ]
                int S, int gmask) {
    __shared__ __align__(16) unsigned short lds_k[TILE_ELT];      // 16 KB
    __shared__ __align__(16) unsigned short lds_v[TILE_ELT];      // 16 KB
    __shared__ __align__(16) unsigned short lds_p[4][32 * KVT];   // 16 KB

    const int tid = threadIdx.x;
    const int lane = tid & 63;
    const int wv = tid >> 6;
    const int row16 = lane & 15;
    const int g = lane >> 4;

    // bijective odd-multiplier perm decorrelates (b,qt,s) from CU slot
    const int wid = (blockIdx.x * 1031) & gmask;
    const int b  = wid & 15;
    const int qt = (wid >> 4) & 15;      // 16 q-tiles of 128 rows
    const int s  = wid >> 8;             // split id
    const int q0 = qt * 128 + wv * 32;
    const int vl = vlg[b];

    const int nt = (vl == 0) ? NTILE : ((vl + KVT - 1) >> 6);

    if (s >= nt) {
        // inactive split: mark ell = 0 for our 128 rows (ws is poisoned!)
        if (tid < 128)
            ellg[(size_t)s * NB * NQ + (size_t)b * NQ + qt * 128 + tid] = 0.f;
        return;
    }

    // Q fragments, 2 row-groups; scale folded: (1/sqrt(128)) * log2(e)
    const float QS = 1.4426950408889634f * 0.08838834764831845f;
    short8 qf[2][4];
    #pragma unroll
    for (int m = 0; m < 2; ++m) {
        const float* qp = qg + ((size_t)b * NQ + q0 + m * 16 + row16) * DH + g * 8;
        #pragma unroll
        for (int c = 0; c < 4; ++c) {
            f32x4 a  = *(const f32x4*)(qp + c * 32);
            f32x4 bb = *(const f32x4*)(qp + c * 32 + 4);
            union { short8 v; unsigned short u[8]; } t;
            #pragma unroll
            for (int j = 0; j < 4; ++j) { t.u[j] = f2bf(a[j] * QS); t.u[4 + j] = f2bf(bb[j] * QS); }
            qf[m][c] = t.v;
        }
    }

    // unnormalized softmax: P = exp2(s); masked -> 0 exactly. vl==0 -> uniform.
    const float MASKV = (vl == 0) ? 0.0f : -1442695.0f;

    f32x4 oacc[2][8];
    f32x4 ellacc[2];
    #pragma unroll
    for (int m = 0; m < 2; ++m) {
        ellacc[m] = (f32x4){0.f, 0.f, 0.f, 0.f};
        #pragma unroll
        for (int n = 0; n < 8; ++n) oacc[m][n] = (f32x4){0.f, 0.f, 0.f, 0.f};
    }
    short8 ones;
    {
        union { short8 v; unsigned short u[8]; } t;
        #pragma unroll
        for (int j = 0; j < 8; ++j) t.u[j] = 0x3F80;  // bf16 1.0
        ones = t.v;
    }

    const char* kbase = (const char*)kws + (size_t)b * NTILE * TILE_BYTES;
    const char* vbase = (const char*)vws + (size_t)b * NTILE * TILE_BYTES;
    const int swzr = ((row16 >> 2) ^ ((row16 & 3) << 1)) & 7;

    for (int tt = s; tt < nt; tt += S) {
        // ---- stage: all K issues first, then V (so vmcnt(4) == K landed) ----
        const char* ks = kbase + (size_t)tt * TILE_BYTES;
        const char* vs = vbase + (size_t)tt * TILE_BYTES;
        #pragma unroll
        for (int i = 0; i < 4; ++i) {
            int off = i * 4096 + wv * 1024;
            load_lds16(ks + off + lane * 16, (char*)lds_k + off);
        }
        #pragma unroll
        for (int i = 0; i < 4; ++i) {
            int off = i * 4096 + wv * 1024;
            load_lds16(vs + off + lane * 16, (char*)lds_v + off);
        }
        asm volatile("s_waitcnt vmcnt(4)" ::: "memory");   // own K done
        __syncthreads();                                    // all K visible

        // ---- QK^T (V still in flight underneath) ----
        f32x4 sc[2][4];
        #pragma unroll
        for (int m = 0; m < 2; ++m)
            #pragma unroll
            for (int n = 0; n < 4; ++n) sc[m][n] = (f32x4){0.f, 0.f, 0.f, 0.f};
        __builtin_amdgcn_s_setprio(1);
        #pragma unroll
        for (int c = 0; c < 4; ++c) {
            short8 kf[4];
            #pragma unroll
            for (int n = 0; n < 4; ++n) {
                int krow = n * 16 + row16;
                kf[n] = *(const short8*)((const char*)lds_k + krow * 256 +
                                         ((c * 64 + g * 16) ^ ((krow & 7) << 4)));
            }
            #pragma unroll
            for (int n = 0; n < 4; ++n)
                #pragma unroll
                for (int m = 0; m < 2; ++m)
                    sc[m][n] = __builtin_amdgcn_mfma_f32_16x16x32_bf16(qf[m][c], kf[n], sc[m][n], 0, 0, 0);
        }
        __builtin_amdgcn_s_setprio(0);

        // ---- mask (global last tile only; vl==0 masks all to 0) ----
        if (vl == 0 || tt == nt - 1) {
            int kvb = tt * KVT;
            #pragma unroll
            for (int n = 0; n < 4; ++n) {
                if (kvb + n * 16 + row16 >= vl) {
                    #pragma unroll
                    for (int m = 0; m < 2; ++m)
                        #pragma unroll
                        for (int r = 0; r < 4; ++r) sc[m][n][r] = MASKV;
                }
            }
        }

        // ---- P = exp2(s) -> per-wave LDS (swizzled) ----
        #pragma unroll
        for (int m = 0; m < 2; ++m)
            #pragma unroll
            for (int n = 0; n < 4; ++n)
                #pragma unroll
                for (int r = 0; r < 4; ++r) {
                    float p = __builtin_amdgcn_exp2f(sc[m][n][r]);
                    int qr = m * 16 + g * 4 + r;
                    int swz = (g ^ (r << 1)) & 7;
                    __hip_bfloat16 h = __float2bfloat16(p);
                    *(unsigned short*)((char*)lds_p[wv] + qr * 128 +
                                       (((n * 16 + row16) * 2) ^ (swz << 4))) =
                        *reinterpret_cast<unsigned short*>(&h);
                }
        asm volatile("s_waitcnt lgkmcnt(0)" ::: "memory");

        asm volatile("s_waitcnt vmcnt(0)" ::: "memory");   // own V done
        __syncthreads();                                    // all V visible

        // ---- PV + ell (ones-column MFMA) ----
        __builtin_amdgcn_s_setprio(1);
        #pragma unroll
        for (int kc = 0; kc < 2; ++kc) {
            short8 pf[2];
            #pragma unroll
            for (int m = 0; m < 2; ++m) {
                pf[m] = *(const short8*)((const char*)lds_p[wv] + (m * 16 + row16) * 128 +
                                         ((kc * 64 + g * 16) ^ (swzr << 4)));
                ellacc[m] = __builtin_amdgcn_mfma_f32_16x16x32_bf16(pf[m], ones, ellacc[m], 0, 0, 0);
            }
            #pragma unroll
            for (int n2 = 0; n2 < 8; ++n2) {
                int vrow = n2 * 16 + row16;
                short8 vf = *(const short8*)((const char*)lds_v + vrow * 128 +
                                             ((kc * 64 + g * 16) ^ ((vrow & 7) << 4)));
                #pragma unroll
                for (int m = 0; m < 2; ++m)
                    oacc[m][n2] = __builtin_amdgcn_mfma_f32_16x16x32_bf16(pf[m], vf, oacc[m][n2], 0, 0, 0);
            }
        }
        __builtin_amdgcn_s_setprio(0);

        __syncthreads();   // all waves done reading before next stage overwrites
    }

    if (S == 1) {
        float* ob = og + ((size_t)b * NQ + q0) * DH;
        #pragma unroll
        for (int m = 0; m < 2; ++m) {
            float rl[4];
            #pragma unroll
            for (int r = 0; r < 4; ++r) rl[r] = 1.0f / ellacc[m][r];
            #pragma unroll
            for (int n2 = 0; n2 < 8; ++n2)
                #pragma unroll
                for (int r = 0; r < 4; ++r)
                    ob[(size_t)(m * 16 + g * 4 + r) * DH + n2 * 16 + row16] = oacc[m][n2][r] * rl[r];
        }
    } else {
        float* op = opart + ((size_t)s * NB * NQ + (size_t)b * NQ + q0) * DH;
        #pragma unroll
        for (int m = 0; m < 2; ++m)
            #pragma unroll
            for (int n2 = 0; n2 < 8; ++n2)
                #pragma unroll
                for (int r = 0; r < 4; ++r)
                    op[(size_t)(m * 16 + g * 4 + r) * DH + n2 * 16 + row16] = oacc[m][n2][r];
        if (row16 == 0) {
            float* el = ellg + (size_t)s * NB * NQ + (size_t)b * NQ + q0;
            #pragma unroll
            for (int m = 0; m < 2; ++m)
                #pragma unroll
                for (int r = 0; r < 4; ++r) el[m * 16 + g * 4 + r] = ellacc[m][r];
        }
    }
}

// ---------------- combine: out = sum_s O_s / sum_s ell_s --------------------
__global__ __launch_bounds__(256)
void combine(const float* __restrict__ opart, const float* __restrict__ ellg,
             float* __restrict__ og, int S) {
    int idx = blockIdx.x * 256 + threadIdx.x;   // NB*NQ*32 threads
    int row = idx >> 5;                          // b*NQ + q
    int c   = idx & 31;                          // float4 chunk of DH
    f32x4 acc = (f32x4){0.f, 0.f, 0.f, 0.f};
    float l = 0.f;
    for (int s = 0; s < S; ++s) {
        float le = ellg[(size_t)s * NB * NQ + row];
        if (le != 0.f) {
            acc += ((const f32x4*)opart)[((size_t)s * NB * NQ + row) * 32 + c];
            l += le;
        }
    }
    float rl = 1.0f / l;
    ((f32x4*)og)[(size_t)row * 32 + c] = acc * rl;
}

extern "C" void kernel_launch(void* const* d_in, const int* in_sizes, int n_in,
                              void* d_out, int out_size, void* d_ws, size_t ws_size,
                              hipStream_t stream) {
    const float* q  = (const float*)d_in[0];
    const float* k  = (const float*)d_in[1];
    const float* v  = (const float*)d_in[2];
    const int*   vl = (const int*)d_in[3];
    float* o = (float*)d_out;

    const size_t IMG = (size_t)NB * NTILE * TILE_BYTES;        // 8 MB
    const size_t ELL_OFF = 2 * IMG;                            // 16 MB
    const size_t ELL_MAX = (size_t)4 * NB * NQ * 4;            // 512 KB
    const size_t OP_OFF  = ELL_OFF + ELL_MAX;
    const size_t OP_ONE  = (size_t)NB * NQ * DH * 4;           // 16 MB per split

    int S = 1;
    if (ws_size >= OP_OFF + 4 * OP_ONE) S = 4;
    else if (ws_size >= OP_OFF + 2 * OP_ONE) S = 2;

    unsigned short* kws = (unsigned short*)d_ws;
    unsigned short* vws = (unsigned short*)((char*)d_ws + IMG);
    float* ellg  = (float*)((char*)d_ws + ELL_OFF);
    float* opart = (float*)((char*)d_ws + OP_OFF);

    int grid = NB * 16 * S;                 // power of two for S in {1,2,4}
    preconv<<<dim3(NB * NTILE), dim3(256), 0, stream>>>(k, v, vl, kws, vws);
    attn_split<<<dim3(grid), dim3(256), 0, stream>>>(q, kws, vws, vl, o, opart, ellg, S, grid - 1);
    if (S > 1)
        combine<<<dim3(NB * NQ * 32 / 256), dim3(256), 0, stream>>>(opart, ellg, o, S);
}

// Round 8
// 61.366 us; speedup vs baseline: 1.3854x; 1.3854x over previous
//
#include <hip/hip_runtime.h>
#include <hip/hip_bf16.h>

#define NB    16
#define NQ    2048
#define NKV   2048
#define DH    128
#define KVT   32
#define NT    64              // tiles per batch
#define TIMG  8192            // bytes per tile image (K or V^T)

typedef __attribute__((ext_vector_type(8)))  short  short8;
typedef __attribute__((ext_vector_type(4)))  float  f32x4;
typedef __attribute__((ext_vector_type(2)))  float  f32x2;
typedef __attribute__((ext_vector_type(16))) float  f32x16;
typedef __attribute__((ext_vector_type(2)))  unsigned int u32x2;

__device__ __forceinline__ unsigned short f2bf(float f) {
    union { float f; unsigned int u; } x; x.f = f;
    unsigned int r = (x.u + 0x7fffu + ((x.u >> 16) & 1u)) >> 16;
    return (unsigned short)r;
}

__device__ __forceinline__ float u2f(unsigned int u) {
    union { unsigned int u; float f; } x; x.u = u; return x.f;
}

__device__ __forceinline__ void load_lds16(const void* g, void* l) {
    __builtin_amdgcn_global_load_lds(
        (const __attribute__((address_space(1))) unsigned int*)g,
        (__attribute__((address_space(3))) unsigned int*)l, 16, 0, 0);
}

// ---- pre-convert: K -> bf16 swizzled tile images, V -> V^T bf16 images ----
// K image (per 32-kv tile): byte(kv, ch16B) = kv*256 + ((ch*16) ^ ((kv&15)<<4))
// V^T image: byte(d, w8kv)  = (d>>2)*256 + 16*((w + 4*(d&3)) ^ ((d>>2)&15))
__global__ __launch_bounds__(256)
void preconv(const float* __restrict__ kg, const float* __restrict__ vg,
             const int* __restrict__ vlg, char* __restrict__ kws,
             char* __restrict__ vws) {
    const int tid = threadIdx.x;
    const int bid = blockIdx.x;
    const int b = bid & 15, t = bid >> 4;     // t: 0..63
    const int vl = vlg[b];
    const int nt = (vl == 0) ? NT : ((vl + KVT - 1) >> 5);
    if (t >= nt) return;

    const float* kb = kg + ((size_t)b * NKV + t * KVT) * DH;
    const float* vb = vg + ((size_t)b * NKV + t * KVT) * DH;
    char* kimg = kws + (size_t)(b * NT + t) * TIMG;
    char* vimg = vws + (size_t)(b * NT + t) * TIMG;

    // K: 32 rows x 16 chunks of 16B (coalesced reads)
    #pragma unroll
    for (int p = 0; p < 2; ++p) {
        int idx = p * 256 + tid;
        int kv = idx >> 4, ch = idx & 15;
        f32x4 a = *(const f32x4*)(kb + kv * DH + ch * 8);
        f32x4 c = *(const f32x4*)(kb + kv * DH + ch * 8 + 4);
        union { short8 v; unsigned short u[8]; } w;
        #pragma unroll
        for (int j = 0; j < 4; ++j) { w.u[j] = f2bf(a[j]); w.u[4 + j] = f2bf(c[j]); }
        *(short8*)(kimg + kv * 256 + ((ch * 16) ^ ((kv & 15) << 4))) = w.v;
    }
    // V^T: 128 d x 4 chunks of 8 kv (strided reads, L2-absorbed; coalesced writes)
    #pragma unroll
    for (int p = 0; p < 2; ++p) {
        int task = p * 256 + tid;
        int w = task & 3, d = task >> 2;
        union { short8 v; unsigned short u[8]; } o;
        #pragma unroll
        for (int j = 0; j < 8; ++j) o.u[j] = f2bf(vb[(w * 8 + j) * DH + d]);
        int byte = (d >> 2) * 256 + 16 * ((w + 4 * (d & 3)) ^ ((d >> 2) & 15));
        *(short8*)(vimg + byte) = o.v;
    }
}

// ---- main attention: swapped-QK 32x32 MFMA, in-register P, dbuf K/V ----
__global__ __launch_bounds__(256, 3)
void attn32(const float* __restrict__ qg, const char* __restrict__ kws,
            const char* __restrict__ vws, const int* __restrict__ vlg,
            float* __restrict__ og, unsigned int* __restrict__ opart,
            float* __restrict__ ellg, int S) {
    __shared__ __align__(16) char smem[32768];   // K dbuf 16KB + V dbuf 16KB

    const int tid  = threadIdx.x;
    const int lane = tid & 63;
    const int wv   = tid >> 6;
    const int l31  = lane & 31;
    const int h    = lane >> 5;

    const int bid = blockIdx.x;
    const int b  = bid & 15;
    const int qt = (bid >> 4) & 15;      // 16 q-tiles of 128 rows
    const int s  = bid >> 8;             // split id
    const int q0 = qt * 128 + wv * 32;
    const int vl = vlg[b];
    const int nt = (vl == 0) ? NT : ((vl + KVT - 1) >> 5);

    if (s >= nt) {
        if (S > 1 && tid < 128)
            ellg[(size_t)s * NB * NQ + (size_t)b * NQ + qt * 128 + tid] = 0.f;
        return;
    }

    // Q fragment (B-operand, swapped): lane holds Q[q=q0+l31][d=c16*16+h*8+j]
    const float QS = 1.4426950408889634f * 0.08838834764831845f;
    short8 qw[8];
    {
        const float* qp = qg + ((size_t)b * NQ + q0 + l31) * DH + h * 8;
        #pragma unroll
        for (int c = 0; c < 8; ++c) {
            f32x4 a  = *(const f32x4*)(qp + c * 16);
            f32x4 bb = *(const f32x4*)(qp + c * 16 + 4);
            union { short8 v; unsigned short u[8]; } t;
            #pragma unroll
            for (int j = 0; j < 4; ++j) { t.u[j] = f2bf(a[j] * QS); t.u[4 + j] = f2bf(bb[j] * QS); }
            qw[c] = t.v;
        }
    }

    const float MASKV = (vl == 0) ? 0.0f : -1442695.0f;   // -1e6*log2(e)
    f32x16 oacc[4];
    #pragma unroll
    for (int d = 0; d < 4; ++d) oacc[d] = (f32x16)(0.0f);
    float esum = 0.f;

    const char* kbase = kws + (size_t)b * NT * TIMG;
    const char* vbase = vws + (size_t)b * NT * TIMG;

    // stage one tile (K 8KB + V 8KB), 4 loads/wave
    auto issue = [&](int t, int pb) {
        const char* ks = kbase + (size_t)t * TIMG;
        const char* vs = vbase + (size_t)t * TIMG;
        char* kd = smem + pb * 8192;
        char* vd = smem + 16384 + pb * 8192;
        #pragma unroll
        for (int i = 0; i < 2; ++i) {
            int off = wv * 2048 + i * 1024;
            load_lds16(ks + off + lane * 16, kd + off);
        }
        #pragma unroll
        for (int i = 0; i < 2; ++i) {
            int off = wv * 2048 + i * 1024;
            load_lds16(vs + off + lane * 16, vd + off);
        }
    };

    issue(s, 0);
    int p = 0;
    const int l15s = (l31 & 15) << 4;

    for (int tt = s; tt < nt; tt += S) {
        asm volatile("s_waitcnt vmcnt(0)" ::: "memory");  // this tile's loads done
        __syncthreads();                                   // all waves' loads + buf free
        int tn = tt + S;
        if (tn < nt) issue(tn, p ^ 1);                     // prefetch under compute

        const char* kb = smem + p * 8192;
        const char* vb = smem + 16384 + p * 8192;

        // ---- QK^T swapped: sc[r] = S^T[kv=tt*32+(r&3)+8*(r>>2)+4h][q=q0+l31] ----
        f32x16 sc = (f32x16)(0.0f);
        __builtin_amdgcn_s_setprio(1);
        #pragma unroll
        for (int c = 0; c < 8; ++c) {
            short8 kf = *(const short8*)(kb + l31 * 256 + ((c * 32 + h * 16) ^ l15s));
            sc = __builtin_amdgcn_mfma_f32_32x32x16_bf16(kf, qw[c], sc, 0, 0, 0);
        }
        __builtin_amdgcn_s_setprio(0);

        // ---- mask (global last tile only; vl==0 masks all to 0 -> P=1) ----
        if (vl == 0 || tt == nt - 1) {
            int kvb = tt * 32 + 4 * h;
            #pragma unroll
            for (int r = 0; r < 16; ++r) {
                int kvg = kvb + (r & 3) + 8 * (r >> 2);
                if (kvg >= vl) sc[r] = MASKV;
            }
        }

        // ---- P = exp2(sc) in-register; ell partial via tree sum ----
        float pe[16];
        #pragma unroll
        for (int r = 0; r < 16; ++r) pe[r] = __builtin_amdgcn_exp2f(sc[r]);
        esum += (((pe[0] + pe[1]) + (pe[2] + pe[3])) + ((pe[4] + pe[5]) + (pe[6] + pe[7])))
              + (((pe[8] + pe[9]) + (pe[10] + pe[11])) + ((pe[12] + pe[13]) + (pe[14] + pe[15])));

        // ---- pack to bf16 + permlane32_swap -> PV B-fragments (no LDS!) ----
        unsigned int A, B, C, D, E, F, G, H;
        asm("v_cvt_pk_bf16_f32 %0, %1, %2" : "=v"(A) : "v"(pe[0]),  "v"(pe[1]));
        asm("v_cvt_pk_bf16_f32 %0, %1, %2" : "=v"(B) : "v"(pe[2]),  "v"(pe[3]));
        asm("v_cvt_pk_bf16_f32 %0, %1, %2" : "=v"(C) : "v"(pe[4]),  "v"(pe[5]));
        asm("v_cvt_pk_bf16_f32 %0, %1, %2" : "=v"(D) : "v"(pe[6]),  "v"(pe[7]));
        asm("v_cvt_pk_bf16_f32 %0, %1, %2" : "=v"(E) : "v"(pe[8]),  "v"(pe[9]));
        asm("v_cvt_pk_bf16_f32 %0, %1, %2" : "=v"(F) : "v"(pe[10]), "v"(pe[11]));
        asm("v_cvt_pk_bf16_f32 %0, %1, %2" : "=v"(G) : "v"(pe[12]), "v"(pe[13]));
        asm("v_cvt_pk_bf16_f32 %0, %1, %2" : "=v"(H) : "v"(pe[14]), "v"(pe[15]));
        asm("v_permlane32_swap_b32 %0, %1" : "+v"(A), "+v"(C));
        asm("v_permlane32_swap_b32 %0, %1" : "+v"(B), "+v"(D));
        asm("v_permlane32_swap_b32 %0, %1" : "+v"(E), "+v"(G));
        asm("v_permlane32_swap_b32 %0, %1" : "+v"(F), "+v"(H));
        union { short8 v; unsigned int w[4]; } P0, P1;
        P0.w[0] = A; P0.w[1] = B; P0.w[2] = C; P0.w[3] = D;   // kv chunk 0..15
        P1.w[0] = E; P1.w[1] = F; P1.w[2] = G; P1.w[3] = H;   // kv chunk 16..31
        short8 pa[2] = { P0.v, P1.v };

        // ---- PV: O^T[d][q] += V^T * P ----
        __builtin_amdgcn_s_setprio(1);
        #pragma unroll
        for (int dblk = 0; dblk < 4; ++dblk) {
            int quad = dblk * 8 + (l31 >> 2);
            int xk = quad & 15;
            #pragma unroll
            for (int c16 = 0; c16 < 2; ++c16) {
                int w = c16 * 2 + h;
                short8 vf = *(const short8*)(vb + quad * 256 +
                                             16 * ((w + 4 * (l31 & 3)) ^ xk));
                oacc[dblk] = __builtin_amdgcn_mfma_f32_32x32x16_bf16(vf, pa[c16], oacc[dblk], 0, 0, 0);
            }
        }
        __builtin_amdgcn_s_setprio(0);
        p ^= 1;
    }

    // ---- ell: add the other lane-half's partial (same q lives at lane^32) ----
    float ea = esum, eb;
    asm volatile("v_mov_b32 %0, %1" : "=v"(eb) : "v"(esum));
    asm("v_permlane32_swap_b32 %0, %1" : "+v"(ea), "+v"(eb));
    float ell = ea + eb;

    __syncthreads();   // staging/compute done; smem reusable for transpose

    if (S > 1 && lane < 32)
        ellg[(size_t)s * NB * NQ + (size_t)b * NQ + q0 + lane] = ell;

    // ---- epilogue: per-wave LDS transpose O^T -> O rows, coalesced stores ----
    float* tw = (float*)smem + wv * 1120;          // 34-stride region + ell row
    if (lane < 32) tw[1088 + l31] = 1.0f / ell;
    unsigned int* opw = opart + ((size_t)s * NB * NQ + (size_t)b * NQ + q0) * 64;
    float* ogp = og + ((size_t)b * NQ + q0) * DH;

    #pragma unroll
    for (int dblk = 0; dblk < 4; ++dblk) {
        #pragma unroll
        for (int r = 0; r < 16; ++r) {
            int dd = (r & 3) + 8 * (r >> 2) + 4 * h;
            tw[l31 * 34 + dd] = oacc[dblk][r];
        }
        #pragma unroll
        for (int pp = 0; pp < 8; ++pp) {
            int qq = pp * 4 + (lane >> 4);
            int cc = lane & 15;
            f32x2 v = *(f32x2*)(tw + qq * 34 + cc * 2);
            if (S == 1) {
                float rl = tw[1088 + qq];
                f32x2 o = { v[0] * rl, v[1] * rl };
                *(f32x2*)(ogp + (size_t)qq * DH + dblk * 32 + cc * 2) = o;
            } else {
                unsigned int w;
                asm("v_cvt_pk_bf16_f32 %0, %1, %2" : "=v"(w) : "v"(v[0]), "v"(v[1]));
                opw[(size_t)qq * 64 + dblk * 16 + cc] = w;
            }
        }
    }
}

// ---- combine: out = (sum_s O_s) / (sum_s ell_s), O_s stored bf16-packed ----
__global__ __launch_bounds__(256)
void combine(const unsigned int* __restrict__ opart, const float* __restrict__ ellg,
             float* __restrict__ og, int S) {
    int idx = blockIdx.x * 256 + threadIdx.x;    // NB*NQ*32 threads
    int row = idx >> 5;                           // b*NQ + q
    int c   = idx & 31;                           // handles d = c*4 .. c*4+3
    float a0 = 0.f, a1 = 0.f, a2 = 0.f, a3 = 0.f, l = 0.f;
    for (int s = 0; s < S; ++s) {
        float le = ellg[(size_t)s * NB * NQ + row];
        if (le != 0.f) {
            l += le;
            u32x2 w = *(const u32x2*)(opart + ((size_t)s * NB * NQ + row) * 64 + c * 2);
            a0 += u2f(w[0] << 16); a1 += u2f(w[0] & 0xffff0000u);
            a2 += u2f(w[1] << 16); a3 += u2f(w[1] & 0xffff0000u);
        }
    }
    float rl = 1.0f / l;
    f32x4 o = { a0 * rl, a1 * rl, a2 * rl, a3 * rl };
    *(f32x4*)(og + (size_t)row * DH + c * 4) = o;
}

extern "C" void kernel_launch(void* const* d_in, const int* in_sizes, int n_in,
                              void* d_out, int out_size, void* d_ws, size_t ws_size,
                              hipStream_t stream) {
    const float* q  = (const float*)d_in[0];
    const float* k  = (const float*)d_in[1];
    const float* v  = (const float*)d_in[2];
    const int*   vl = (const int*)d_in[3];
    float* o = (float*)d_out;

    const size_t IMG     = (size_t)NB * NT * TIMG;          // 8 MB per image set
    const size_t ELL_OFF = 2 * IMG;                         // 16 MB
    const size_t ELL_MAX = (size_t)4 * NB * NQ * 4;         // 512 KB
    const size_t OP_OFF  = ELL_OFF + ELL_MAX;
    const size_t OP_ONE  = (size_t)NB * NQ * DH * 2;        // 8 MB per split (bf16)

    int S = 1;
    if (ws_size >= OP_OFF + 4 * OP_ONE) S = 4;
    else if (ws_size >= OP_OFF + 2 * OP_ONE) S = 2;

    char* kws = (char*)d_ws;
    char* vws = (char*)d_ws + IMG;
    float* ellg = (float*)((char*)d_ws + ELL_OFF);
    unsigned int* opart = (unsigned int*)((char*)d_ws + OP_OFF);

    preconv<<<dim3(NB * NT), dim3(256), 0, stream>>>(k, v, vl, kws, vws);
    attn32<<<dim3(256 * S), dim3(256), 0, stream>>>(q, kws, vws, vl, o, opart, ellg, S);
    if (S > 1)
        combine<<<dim3(NB * NQ * 32 / 256), dim3(256), 0, stream>>>(opart, ellg, o, S);
}